// Round 16
// baseline (183.179 us; speedup 1.0000x reference)
//
#include <hip/hip_runtime.h>
#include <cstdint>

constexpr int BG = 256;        // graphs
constexpr int MAXN = 2000;
constexpr int NPARTS = 10;

// ---------------- utility: fast zero (grid-stride int4) ----------------

__global__ void k_zeroi(int4* __restrict__ p, size_t n4) {
  size_t i = (size_t)blockIdx.x * blockDim.x + threadIdx.x;
  size_t stride = (size_t)gridDim.x * blockDim.x;
  for (; i < n4; i += stride) p[i] = make_int4(0, 0, 0, 0);
}

// zero only padding positions of dense: pos in [cnt, MAXN) per graph/channel
__global__ void k_zero_pad(float* __restrict__ dense, const int* __restrict__ cum) {
  int b = blockIdx.x;
  int cnt = cum[b + 1] - cum[b];
  for (int pos = cnt + threadIdx.x; pos < MAXN; pos += blockDim.x) {
    #pragma unroll
    for (int c = 0; c < 8; c++)
      dense[((size_t)(b * 8 + c)) * MAXN + pos] = 0.f;
  }
}

// ---------------- batch boundaries (no atomics; batch is sorted) ----------------

__global__ void k_bounds(const int* __restrict__ batch, int* __restrict__ cum, int N) {
  int i = blockIdx.x * blockDim.x + threadIdx.x;
  if (i >= N) return;
  int b = batch[i];
  if (i == 0) cum[b] = 0;
  else if (batch[i - 1] != b) cum[b] = i;
  if (i == N - 1) cum[BG] = N;
}

// ---------------- CSR build ----------------

__global__ void k_deg_int(const int* __restrict__ dst, int* __restrict__ deg, int E) {
  int e = blockIdx.x * blockDim.x + threadIdx.x;
  if (e < E) atomicAdd(&deg[dst[e]], 1);
}

__global__ void k_blocksum(const int* __restrict__ deg, int* __restrict__ bsum, int N) {
  __shared__ int sd[256];
  int i = blockIdx.x * 256 + threadIdx.x;
  sd[threadIdx.x] = (i < N) ? deg[i] : 0;
  __syncthreads();
  for (int s = 128; s > 0; s >>= 1) {
    if (threadIdx.x < s) sd[threadIdx.x] += sd[threadIdx.x + s];
    __syncthreads();
  }
  if (threadIdx.x == 0) bsum[blockIdx.x] = sd[0];
}

// parallel exclusive scan of bsum[0..nb) with one 256-thread block
__global__ __launch_bounds__(256)
void k_scanb(int* __restrict__ bsum, int nb) {
  __shared__ int part[256];
  int tid = threadIdx.x;
  int per = (nb + 255) / 256;
  int beg = tid * per;
  int end = beg + per; if (end > nb) end = nb;
  int s = 0;
  for (int i = beg; i < end; i++) s += bsum[i];
  part[tid] = s;
  __syncthreads();
  for (int off = 1; off < 256; off <<= 1) {
    int t = (tid >= off) ? part[tid - off] : 0;
    __syncthreads();
    part[tid] += t;
    __syncthreads();
  }
  int run = part[tid] - s;   // exclusive prefix of this chunk
  for (int i = beg; i < end; i++) { int v = bsum[i]; bsum[i] = run; run += v; }
}

// rowptr + dinv fused (deg already loaded here)
__global__ void k_rowptr(const int* __restrict__ deg, const int* __restrict__ bsum,
                         int* __restrict__ rowptr, float* __restrict__ dinvf, int N) {
  __shared__ int sc[256];
  int tid = threadIdx.x;
  int i = blockIdx.x * 256 + tid;
  int v = (i < N) ? deg[i] : 0;
  sc[tid] = v;
  __syncthreads();
  for (int off = 1; off < 256; off <<= 1) {
    int t = (tid >= off) ? sc[tid - off] : 0;
    __syncthreads();
    sc[tid] += t;
    __syncthreads();
  }
  if (i < N) {
    rowptr[i] = bsum[blockIdx.x] + sc[tid] - v;   // exclusive
    dinvf[i] = rsqrtf((float)v + 1.0f);           // +1 self-loop
  }
  if (i == N - 1) rowptr[N] = bsum[blockIdx.x] + sc[tid];  // total = E
}

__global__ void k_fill(const int* __restrict__ src, const int* __restrict__ dst,
                       const int* __restrict__ rowptr, int* __restrict__ cursor,
                       int* __restrict__ adj, int E) {
  int e = blockIdx.x * blockDim.x + threadIdx.x;
  if (e >= E) return;
  int d = dst[e];
  int p = atomicAdd(&cursor[d], 1);
  adj[rowptr[d] + p] = src[e];
}

// ---------------- GCN dense parts ----------------

__global__ void k_xw1(const float* __restrict__ x, const float* __restrict__ W1,
                      const float* __restrict__ dinv, float* __restrict__ A, int N) {
  int i = blockIdx.x * blockDim.x + threadIdx.x;
  if (i >= N) return;
  float4 xi = ((const float4*)x)[i];
  float di = dinv[i];
  #pragma unroll
  for (int c = 0; c < 8; c++) {
    float s = xi.x * W1[c] + xi.y * W1[8 + c] + xi.z * W1[16 + c] + xi.w * W1[24 + c];
    A[(size_t)i * 8 + c] = s * di;
  }
}

__global__ void k_gather_l1(const float* __restrict__ A, const int* __restrict__ rowptr,
                            const int* __restrict__ adj, const float* __restrict__ dinv,
                            const float* __restrict__ b1, const float* __restrict__ W2,
                            float* __restrict__ A2, int N) {
  int i = blockIdx.x * blockDim.x + threadIdx.x;
  if (i >= N) return;
  const float4* Ai = (const float4*)(A + (size_t)i * 8);
  float4 s0 = Ai[0], s1 = Ai[1];
  int beg = rowptr[i], end = rowptr[i + 1];
  for (int j = beg; j < end; j++) {
    const float4* As = (const float4*)(A + (size_t)adj[j] * 8);
    float4 a0 = As[0], a1 = As[1];
    s0.x += a0.x; s0.y += a0.y; s0.z += a0.z; s0.w += a0.w;
    s1.x += a1.x; s1.y += a1.y; s1.z += a1.z; s1.w += a1.w;
  }
  float di = dinv[i];
  float h[8];
  h[0] = fmaxf(s0.x * di + b1[0], 0.f); h[1] = fmaxf(s0.y * di + b1[1], 0.f);
  h[2] = fmaxf(s0.z * di + b1[2], 0.f); h[3] = fmaxf(s0.w * di + b1[3], 0.f);
  h[4] = fmaxf(s1.x * di + b1[4], 0.f); h[5] = fmaxf(s1.y * di + b1[5], 0.f);
  h[6] = fmaxf(s1.z * di + b1[6], 0.f); h[7] = fmaxf(s1.w * di + b1[7], 0.f);
  #pragma unroll
  for (int c = 0; c < 8; c++) {
    float a = 0.f;
    #pragma unroll
    for (int k = 0; k < 8; k++) a += h[k] * W2[k * 8 + c];
    A2[(size_t)i * 8 + c] = a * di;
  }
}

__global__ void k_gather_l2(const float* __restrict__ A2, const int* __restrict__ rowptr,
                            const int* __restrict__ adj, const float* __restrict__ dinv,
                            const float* __restrict__ b2, const int* __restrict__ batch,
                            const int* __restrict__ cum, float* __restrict__ dense, int N) {
  int i = blockIdx.x * blockDim.x + threadIdx.x;
  if (i >= N) return;
  const float4* Ai = (const float4*)(A2 + (size_t)i * 8);
  float4 s0 = Ai[0], s1 = Ai[1];
  int beg = rowptr[i], end = rowptr[i + 1];
  for (int j = beg; j < end; j++) {
    const float4* As = (const float4*)(A2 + (size_t)adj[j] * 8);
    float4 a0 = As[0], a1 = As[1];
    s0.x += a0.x; s0.y += a0.y; s0.z += a0.z; s0.w += a0.w;
    s1.x += a1.x; s1.y += a1.y; s1.z += a1.z; s1.w += a1.w;
  }
  float di = dinv[i];
  float h[8];
  h[0] = fmaxf(s0.x * di + b2[0], 0.f); h[1] = fmaxf(s0.y * di + b2[1], 0.f);
  h[2] = fmaxf(s0.z * di + b2[2], 0.f); h[3] = fmaxf(s0.w * di + b2[3], 0.f);
  h[4] = fmaxf(s1.x * di + b2[4], 0.f); h[5] = fmaxf(s1.y * di + b2[5], 0.f);
  h[6] = fmaxf(s1.z * di + b2[6], 0.f); h[7] = fmaxf(s1.w * di + b2[7], 0.f);
  int b = batch[i];
  int pos = i - cum[b];
  #pragma unroll
  for (int c = 0; c < 8; c++)
    dense[((size_t)(b * 8 + c)) * MAXN + pos] = h[c];
}

// ---------------- conv1d(k=5,'same') + relu + mean-pool2 — LDS input tile ----------------
// One memory-latency exposure per TILE: flat coalesced staging burst (independent dword
// loads, one wait + one barrier), then the whole ci loop runs from LDS:
// per ci per wave: 2 aligned ds_read_b128 + scalar weight loads + 80 FMAs.
// grid (BG, COG, LT). Block: COPB=16 out-channels; wave: NCO=4; lane: 2 pooled positions.
template<int CIN, int COUT, int L, int COG, int LT>
__global__ __launch_bounds__(256)
void k_conv(const float* __restrict__ in, const float* __restrict__ w,
            const float* __restrict__ bias, float* __restrict__ out) {
  constexpr int LOUT = L / 2;
  constexpr int COPB = COUT / COG;      // 16
  constexpr int NCO = COPB / 4;         // 4
  constexpr int TP = 128;               // pooled positions per tile
  constexpr int W = 2 * TP + 4;         // staged cols per ci (260)
  __shared__ float tin[CIN * W];

  const int P0 = blockIdx.z * TP;
  const int c0 = 2 * P0 - 2;            // global col of tile index 0
  const float* __restrict__ inb = in + (size_t)blockIdx.x * CIN * L;

  // flat staging: consecutive threads -> consecutive floats (coalesced, independent)
  for (int idx = threadIdx.x; idx < CIN * W; idx += 256) {
    int ci = idx / W, t = idx - ci * W;
    int gc = c0 + t;
    tin[idx] = (gc >= 0 && gc < L) ? inb[(size_t)ci * L + gc] : 0.f;
  }
  __syncthreads();

  const int lane = threadIdx.x & 63;
  const int wv = threadIdx.x >> 6;
  const int co0 = __builtin_amdgcn_readfirstlane(blockIdx.y * COPB + wv * NCO);
  const int p0 = P0 + lane * 2;         // first pooled pos of this lane

  float acc[NCO][4];
  #pragma unroll
  for (int g = 0; g < NCO; g++)
    #pragma unroll
    for (int q = 0; q < 4; q++) acc[g][q] = 0.f;

  for (int ci = 0; ci < CIN; ci++) {
    // r[j] = tin[ci][4*lane + j], j=0..7  (16B-aligned -> 2x ds_read_b128)
    const float* tp = tin + ci * W + 4 * lane;
    float4 qa = *(const float4*)(tp);
    float4 qb = *(const float4*)(tp + 4);
    float r[8];
    r[0] = qa.x; r[1] = qa.y; r[2] = qa.z; r[3] = qa.w;
    r[4] = qb.x; r[5] = qb.y; r[6] = qb.z; r[7] = qb.w;
    #pragma unroll
    for (int g = 0; g < NCO; g++) {
      const float* wg = w + ((size_t)(co0 + g) * CIN + ci) * 5;  // wave-uniform -> s_load
      float v0 = wg[0], v1 = wg[1], v2 = wg[2], v3 = wg[3], v4 = wg[4];
      #pragma unroll
      for (int q = 0; q < 4; q++)
        acc[g][q] += v0 * r[q] + v1 * r[q + 1] + v2 * r[q + 2]
                   + v3 * r[q + 3] + v4 * r[q + 4];
    }
  }

  #pragma unroll
  for (int g = 0; g < NCO; g++) {
    int co = co0 + g;
    float bv = bias[co];
    float y0 = fmaxf(acc[g][0] + bv, 0.f);
    float y1 = fmaxf(acc[g][1] + bv, 0.f);
    float y2 = fmaxf(acc[g][2] + bv, 0.f);
    float y3 = fmaxf(acc[g][3] + bv, 0.f);
    float t0 = 0.5f * (y0 + y1);
    float t1 = 0.5f * (y2 + y3);
    float* op = out + (size_t)(blockIdx.x * COUT + co) * LOUT + p0;
    if (p0 + 1 < LOUT) {
      *(float2*)op = make_float2(t0, t1);
    } else if (p0 < LOUT) {
      op[0] = t0;
    }
  }
}

// ---------------- fused head: segment means + MLP (one block per graph) ----------------
__global__ __launch_bounds__(256)
void k_head(const float* __restrict__ xp, const int* __restrict__ cum,
            const float* __restrict__ fw1, const float* __restrict__ fb1,
            const float* __restrict__ fw2, const float* __restrict__ fb2,
            float* __restrict__ out) {
  constexpr int LC = MAXN / 8;   // 250
  __shared__ float seg[640];
  __shared__ float hid[100];
  int b = blockIdx.x;
  int valid = (cum[b + 1] - cum[b]) >> 3;
  int base = valid / NPARTS, rem = valid % NPARTS;
  for (int idx = threadIdx.x; idx < 64 * NPARTS; idx += 256) {
    int c = idx / NPARTS, j = idx % NPARTS;
    int size = base + (j < rem ? 1 : 0);
    int start = j * base + (j < rem ? j : rem);
    const float* p = xp + ((size_t)b * 64 + c) * LC + start;
    float s = 0.f;
    for (int t = 0; t < size; t++) s += p[t];
    seg[idx] = s / (float)size;   // seg[c*10+j]
  }
  __syncthreads();
  int t = threadIdx.x;
  if (t < 100) {
    float acc = fb1[t];
    for (int k = 0; k < 640; k++) acc += seg[k] * fw1[(size_t)k * 100 + t];
    hid[t] = fmaxf(acc, 0.f);
  }
  __syncthreads();
  if (t < 2) {
    float acc = fb2[t];
    for (int k = 0; k < 100; k++) acc += hid[k] * fw2[k * 2 + t];
    out[b * 2 + t] = acc;
  }
}

extern "C" void kernel_launch(void* const* d_in, const int* in_sizes, int n_in,
                              void* d_out, int out_size, void* d_ws, size_t ws_size,
                              hipStream_t stream) {
  const float* x   = (const float*)d_in[0];
  const int*   ei  = (const int*)d_in[1];
  const int* batch = (const int*)d_in[2];
  const float* W1  = (const float*)d_in[3];
  const float* b1  = (const float*)d_in[4];
  const float* W2  = (const float*)d_in[5];
  const float* b2  = (const float*)d_in[6];
  const float* cw1 = (const float*)d_in[7];
  const float* cb1 = (const float*)d_in[8];
  const float* cw2 = (const float*)d_in[9];
  const float* cb2 = (const float*)d_in[10];
  const float* cw3 = (const float*)d_in[11];
  const float* cb3 = (const float*)d_in[12];
  const float* fw1 = (const float*)d_in[13];
  const float* fb1 = (const float*)d_in[14];
  const float* fw2 = (const float*)d_in[15];
  const float* fb2 = (const float*)d_in[16];
  float* outp = (float*)d_out;

  int N = in_sizes[0] / 4;
  int E = in_sizes[1] / 2;
  size_t N8 = (size_t)N * 8;
  int nbN = (N + 255) / 256, nbE = (E + 255) / 256;

  float* wsf  = (float*)d_ws;
  float* A    = wsf;
  float* Bb   = A + N8;              // A2 for layer 2
  int* degI   = (int*)(Bb + N8);     // N ints
  int* cursor = degI + N;            // N ints (adjacent -> one zero pass)
  float* dinv = (float*)(cursor + N);// N floats
  int* cum    = (int*)(dinv + N);    // BG+1 ints
  float* D0   = (float*)(((uintptr_t)(cum + BG + 1) + 255) & ~(uintptr_t)255);
  float* D1   = D0 + (size_t)BG * 8 * MAXN;

  // CSR temporaries aliased into D1 (D1 first written by conv1, after fill/gathers)
  int* rowptr = (int*)D1;            // N+1
  int* adj    = rowptr + (N + 1);    // E
  int* bsum   = adj + E;             // nbN

  // --- boundaries (no atomics) ---
  k_bounds<<<nbN, 256, 0, stream>>>(batch, cum, N);

  // --- CSR build ---
  k_zeroi<<<1024, 256, 0, stream>>>((int4*)degI, (size_t)(2 * N) / 4);  // degI + cursor
  k_deg_int<<<nbE, 256, 0, stream>>>(ei + E, degI, E);
  k_blocksum<<<nbN, 256, 0, stream>>>(degI, bsum, N);
  k_scanb<<<1, 256, 0, stream>>>(bsum, nbN);
  k_rowptr<<<nbN, 256, 0, stream>>>(degI, bsum, rowptr, dinv, N);
  k_fill<<<nbE, 256, 0, stream>>>(ei, ei + E, rowptr, cursor, adj, E);

  // --- GCN (gather, no atomics) ---
  k_xw1<<<nbN, 256, 0, stream>>>(x, W1, dinv, A, N);
  k_gather_l1<<<nbN, 256, 0, stream>>>(A, rowptr, adj, dinv, b1, W2, Bb, N);
  k_zero_pad<<<BG, 256, 0, stream>>>(D0, cum);   // zero only pos >= cnt
  k_gather_l2<<<nbN, 256, 0, stream>>>(Bb, rowptr, adj, dinv, b2, batch, cum, D0, N);

  // --- convs: LDS input tile, one latency exposure per tile ---
  k_conv<8, 16, 2000, 1, 8><<<dim3(BG, 1, 8), 256, 0, stream>>>(D0, cw1, cb1, D1);
  k_conv<16, 32, 1000, 2, 4><<<dim3(BG, 2, 4), 256, 0, stream>>>(D1, cw2, cb2, D0);
  k_conv<32, 64, 500, 4, 2><<<dim3(BG, 4, 2), 256, 0, stream>>>(D0, cw3, cb3, D1);

  // --- fused segment means + MLP ---
  k_head<<<BG, 256, 0, stream>>>(D1, cum, fw1, fb1, fw2, fb2, outp);
}

// Round 17
// 162.895 us; speedup vs baseline: 1.1245x; 1.1245x over previous
//
#include <hip/hip_runtime.h>
#include <cstdint>

constexpr int BG = 256;        // graphs
constexpr int MAXN = 2000;
constexpr int NPARTS = 10;

// zero only padding positions of dense: pos in [cnt, MAXN) per graph/channel
__global__ void k_zero_pad(float* __restrict__ dense, const int* __restrict__ cum) {
  int b = blockIdx.x;
  int cnt = cum[b + 1] - cum[b];
  for (int pos = cnt + threadIdx.x; pos < MAXN; pos += blockDim.x) {
    #pragma unroll
    for (int c = 0; c < 8; c++)
      dense[((size_t)(b * 8 + c)) * MAXN + pos] = 0.f;
  }
}

// ---------------- batch boundaries + zero degI/cursor (fused; batch is sorted) ----------------

__global__ void k_bounds(const int* __restrict__ batch, int* __restrict__ cum,
                         int* __restrict__ degI, int* __restrict__ cursor, int N) {
  int i = blockIdx.x * blockDim.x + threadIdx.x;
  if (i >= N) return;
  degI[i] = 0;
  cursor[i] = 0;
  int b = batch[i];
  if (i == 0) cum[b] = 0;
  else if (batch[i - 1] != b) cum[b] = i;
  if (i == N - 1) cum[BG] = N;
}

// ---------------- CSR build ----------------

__global__ void k_deg_int(const int* __restrict__ dst, int* __restrict__ deg, int E) {
  int e = blockIdx.x * blockDim.x + threadIdx.x;
  if (e < E) atomicAdd(&deg[dst[e]], 1);
}

__global__ void k_blocksum(const int* __restrict__ deg, int* __restrict__ bsum, int N) {
  __shared__ int sd[256];
  int i = blockIdx.x * 256 + threadIdx.x;
  sd[threadIdx.x] = (i < N) ? deg[i] : 0;
  __syncthreads();
  for (int s = 128; s > 0; s >>= 1) {
    if (threadIdx.x < s) sd[threadIdx.x] += sd[threadIdx.x + s];
    __syncthreads();
  }
  if (threadIdx.x == 0) bsum[blockIdx.x] = sd[0];
}

// parallel exclusive scan of bsum[0..nb) with one 256-thread block
__global__ __launch_bounds__(256)
void k_scanb(int* __restrict__ bsum, int nb) {
  __shared__ int part[256];
  int tid = threadIdx.x;
  int per = (nb + 255) / 256;
  int beg = tid * per;
  int end = beg + per; if (end > nb) end = nb;
  int s = 0;
  for (int i = beg; i < end; i++) s += bsum[i];
  part[tid] = s;
  __syncthreads();
  for (int off = 1; off < 256; off <<= 1) {
    int t = (tid >= off) ? part[tid - off] : 0;
    __syncthreads();
    part[tid] += t;
    __syncthreads();
  }
  int run = part[tid] - s;   // exclusive prefix of this chunk
  for (int i = beg; i < end; i++) { int v = bsum[i]; bsum[i] = run; run += v; }
}

// rowptr + dinv fused (deg already loaded here)
__global__ void k_rowptr(const int* __restrict__ deg, const int* __restrict__ bsum,
                         int* __restrict__ rowptr, float* __restrict__ dinvf, int N) {
  __shared__ int sc[256];
  int tid = threadIdx.x;
  int i = blockIdx.x * 256 + tid;
  int v = (i < N) ? deg[i] : 0;
  sc[tid] = v;
  __syncthreads();
  for (int off = 1; off < 256; off <<= 1) {
    int t = (tid >= off) ? sc[tid - off] : 0;
    __syncthreads();
    sc[tid] += t;
    __syncthreads();
  }
  if (i < N) {
    rowptr[i] = bsum[blockIdx.x] + sc[tid] - v;   // exclusive
    dinvf[i] = rsqrtf((float)v + 1.0f);           // +1 self-loop
  }
  if (i == N - 1) rowptr[N] = bsum[blockIdx.x] + sc[tid];  // total = E
}

__global__ void k_fill(const int* __restrict__ src, const int* __restrict__ dst,
                       const int* __restrict__ rowptr, int* __restrict__ cursor,
                       int* __restrict__ adj, int E) {
  int e = blockIdx.x * blockDim.x + threadIdx.x;
  if (e >= E) return;
  int d = dst[e];
  int p = atomicAdd(&cursor[d], 1);
  adj[rowptr[d] + p] = src[e];
}

// ---------------- GCN dense parts ----------------

__global__ void k_xw1(const float* __restrict__ x, const float* __restrict__ W1,
                      const float* __restrict__ dinv, float* __restrict__ A, int N) {
  int i = blockIdx.x * blockDim.x + threadIdx.x;
  if (i >= N) return;
  float4 xi = ((const float4*)x)[i];
  float di = dinv[i];
  #pragma unroll
  for (int c = 0; c < 8; c++) {
    float s = xi.x * W1[c] + xi.y * W1[8 + c] + xi.z * W1[16 + c] + xi.w * W1[24 + c];
    A[(size_t)i * 8 + c] = s * di;
  }
}

__global__ void k_gather_l1(const float* __restrict__ A, const int* __restrict__ rowptr,
                            const int* __restrict__ adj, const float* __restrict__ dinv,
                            const float* __restrict__ b1, const float* __restrict__ W2,
                            float* __restrict__ A2, int N) {
  int i = blockIdx.x * blockDim.x + threadIdx.x;
  if (i >= N) return;
  const float4* Ai = (const float4*)(A + (size_t)i * 8);
  float4 s0 = Ai[0], s1 = Ai[1];
  int beg = rowptr[i], end = rowptr[i + 1];
  for (int j = beg; j < end; j++) {
    const float4* As = (const float4*)(A + (size_t)adj[j] * 8);
    float4 a0 = As[0], a1 = As[1];
    s0.x += a0.x; s0.y += a0.y; s0.z += a0.z; s0.w += a0.w;
    s1.x += a1.x; s1.y += a1.y; s1.z += a1.z; s1.w += a1.w;
  }
  float di = dinv[i];
  float h[8];
  h[0] = fmaxf(s0.x * di + b1[0], 0.f); h[1] = fmaxf(s0.y * di + b1[1], 0.f);
  h[2] = fmaxf(s0.z * di + b1[2], 0.f); h[3] = fmaxf(s0.w * di + b1[3], 0.f);
  h[4] = fmaxf(s1.x * di + b1[4], 0.f); h[5] = fmaxf(s1.y * di + b1[5], 0.f);
  h[6] = fmaxf(s1.z * di + b1[6], 0.f); h[7] = fmaxf(s1.w * di + b1[7], 0.f);
  #pragma unroll
  for (int c = 0; c < 8; c++) {
    float a = 0.f;
    #pragma unroll
    for (int k = 0; k < 8; k++) a += h[k] * W2[k * 8 + c];
    A2[(size_t)i * 8 + c] = a * di;
  }
}

__global__ void k_gather_l2(const float* __restrict__ A2, const int* __restrict__ rowptr,
                            const int* __restrict__ adj, const float* __restrict__ dinv,
                            const float* __restrict__ b2, const int* __restrict__ batch,
                            const int* __restrict__ cum, float* __restrict__ dense, int N) {
  int i = blockIdx.x * blockDim.x + threadIdx.x;
  if (i >= N) return;
  const float4* Ai = (const float4*)(A2 + (size_t)i * 8);
  float4 s0 = Ai[0], s1 = Ai[1];
  int beg = rowptr[i], end = rowptr[i + 1];
  for (int j = beg; j < end; j++) {
    const float4* As = (const float4*)(A2 + (size_t)adj[j] * 8);
    float4 a0 = As[0], a1 = As[1];
    s0.x += a0.x; s0.y += a0.y; s0.z += a0.z; s0.w += a0.w;
    s1.x += a1.x; s1.y += a1.y; s1.z += a1.z; s1.w += a1.w;
  }
  float di = dinv[i];
  float h[8];
  h[0] = fmaxf(s0.x * di + b2[0], 0.f); h[1] = fmaxf(s0.y * di + b2[1], 0.f);
  h[2] = fmaxf(s0.z * di + b2[2], 0.f); h[3] = fmaxf(s0.w * di + b2[3], 0.f);
  h[4] = fmaxf(s1.x * di + b2[4], 0.f); h[5] = fmaxf(s1.y * di + b2[5], 0.f);
  h[6] = fmaxf(s1.z * di + b2[6], 0.f); h[7] = fmaxf(s1.w * di + b2[7], 0.f);
  int b = batch[i];
  int pos = i - cum[b];
  #pragma unroll
  for (int c = 0; c < 8; c++)
    dense[((size_t)(b * 8 + c)) * MAXN + pos] = h[c];
}

// ---------------- conv1d(k=5,'same') + relu + mean-pool2 — scalar weights, NCO param ----------------
// grid (BG, COG, LT). Block: COPB=COUT/COG out-channels; wave: NCO=COPB/4; lane: 4 pooled pos.
// Weights via wave-uniform scalar loads (s_load broadcast). 4 aligned float4 input loads/ci;
// bases clamped to [0,L-4]: right-overrun feeds only unstored/unread outputs; left edge zeroes.
// NCO=8 gives 640 FMA-cycles per ci per wave to hide the per-ci load latency.
template<int CIN, int COUT, int L, int COG>
__global__ void k_conv(const float* __restrict__ in, const float* __restrict__ w,
                       const float* __restrict__ bias, float* __restrict__ out) {
  constexpr int LOUT = L / 2;
  constexpr int COPB = COUT / COG;      // out-channels per block
  constexpr int NCO = COPB / 4;         // out-channels per wave (4 or 8)
  constexpr int TP = 256;               // pooled positions per tile

  const int lane = threadIdx.x & 63;
  const int wv = threadIdx.x >> 6;
  const int co0 = __builtin_amdgcn_readfirstlane(blockIdx.y * COPB + wv * NCO);
  const int p0 = blockIdx.z * TP + lane * 4;   // first pooled pos (mult of 4)
  const int a0 = 2 * p0 - 4;                   // aligned load base
  const bool lz = (p0 == 0);
  const float* __restrict__ inb = in + (size_t)blockIdx.x * CIN * L;

  int bas[4];
  #pragma unroll
  for (int m = 0; m < 4; m++) {
    int rb = a0 + 4 * m;
    rb = rb < 0 ? 0 : rb;
    bas[m] = rb > (L - 4) ? (L - 4) : rb;
  }

  float acc[NCO][8];
  #pragma unroll
  for (int g = 0; g < NCO; g++)
    #pragma unroll
    for (int p = 0; p < 8; p++) acc[g][p] = 0.f;

  for (int ci = 0; ci < CIN; ci++) {
    const float* s = inb + (size_t)ci * L;
    float4 q0 = *(const float4*)(s + bas[0]);
    float4 q1 = *(const float4*)(s + bas[1]);
    float4 q2 = *(const float4*)(s + bas[2]);
    float4 q3 = *(const float4*)(s + bas[3]);
    float r[16];
    r[0] = q0.x; r[1] = q0.y; r[2] = q0.z; r[3] = q0.w;
    r[4] = q1.x; r[5] = q1.y; r[6] = q1.z; r[7] = q1.w;
    r[8] = q2.x; r[9] = q2.y; r[10] = q2.z; r[11] = q2.w;
    r[12] = q3.x; r[13] = q3.y; r[14] = q3.z; r[15] = q3.w;
    if (lz) { r[2] = 0.f; r[3] = 0.f; }   // cols -2,-1 (left pad)
    #pragma unroll
    for (int g = 0; g < NCO; g++) {
      const float* wg = w + ((size_t)(co0 + g) * CIN + ci) * 5;  // wave-uniform -> s_load
      float v0 = wg[0], v1 = wg[1], v2 = wg[2], v3 = wg[3], v4 = wg[4];
      #pragma unroll
      for (int p = 0; p < 8; p++)
        acc[g][p] += v0 * r[p + 2] + v1 * r[p + 3] + v2 * r[p + 4]
                   + v3 * r[p + 5] + v4 * r[p + 6];
    }
  }

  #pragma unroll
  for (int g = 0; g < NCO; g++) {
    int co = co0 + g;
    float bv = bias[co];
    float tmp[4];
    #pragma unroll
    for (int m = 0; m < 4; m++) {
      float y0 = fmaxf(acc[g][2 * m] + bv, 0.f);
      float y1 = fmaxf(acc[g][2 * m + 1] + bv, 0.f);
      tmp[m] = 0.5f * (y0 + y1);
    }
    float* op = out + (size_t)(blockIdx.x * COUT + co) * LOUT + p0;
    if constexpr (LOUT % 4 == 0) {
      if (p0 + 4 <= LOUT) {
        *(float4*)op = make_float4(tmp[0], tmp[1], tmp[2], tmp[3]);
      } else {
        #pragma unroll
        for (int m = 0; m < 4; m++) if (p0 + m < LOUT) op[m] = tmp[m];
      }
    } else {  // LOUT % 2 == 0 (conv3: 250)
      #pragma unroll
      for (int m2 = 0; m2 < 2; m2++) {
        int p = p0 + 2 * m2;
        if (p + 1 < LOUT) {
          *(float2*)(op + 2 * m2) = make_float2(tmp[2 * m2], tmp[2 * m2 + 1]);
        } else if (p < LOUT) {
          op[2 * m2] = tmp[2 * m2];
        }
      }
    }
  }
}

// ---------------- fused head: segment means + MLP (one block per graph) ----------------
__global__ __launch_bounds__(256)
void k_head(const float* __restrict__ xp, const int* __restrict__ cum,
            const float* __restrict__ fw1, const float* __restrict__ fb1,
            const float* __restrict__ fw2, const float* __restrict__ fb2,
            float* __restrict__ out) {
  constexpr int LC = MAXN / 8;   // 250
  __shared__ float seg[640];
  __shared__ float hid[100];
  int b = blockIdx.x;
  int valid = (cum[b + 1] - cum[b]) >> 3;
  int base = valid / NPARTS, rem = valid % NPARTS;
  for (int idx = threadIdx.x; idx < 64 * NPARTS; idx += 256) {
    int c = idx / NPARTS, j = idx % NPARTS;
    int size = base + (j < rem ? 1 : 0);
    int start = j * base + (j < rem ? j : rem);
    const float* p = xp + ((size_t)b * 64 + c) * LC + start;
    float s = 0.f;
    for (int t = 0; t < size; t++) s += p[t];
    seg[idx] = s / (float)size;   // seg[c*10+j]
  }
  __syncthreads();
  int t = threadIdx.x;
  if (t < 100) {
    float acc = fb1[t];
    for (int k = 0; k < 640; k++) acc += seg[k] * fw1[(size_t)k * 100 + t];
    hid[t] = fmaxf(acc, 0.f);
  }
  __syncthreads();
  if (t < 2) {
    float acc = fb2[t];
    for (int k = 0; k < 100; k++) acc += hid[k] * fw2[k * 2 + t];
    out[b * 2 + t] = acc;
  }
}

extern "C" void kernel_launch(void* const* d_in, const int* in_sizes, int n_in,
                              void* d_out, int out_size, void* d_ws, size_t ws_size,
                              hipStream_t stream) {
  const float* x   = (const float*)d_in[0];
  const int*   ei  = (const int*)d_in[1];
  const int* batch = (const int*)d_in[2];
  const float* W1  = (const float*)d_in[3];
  const float* b1  = (const float*)d_in[4];
  const float* W2  = (const float*)d_in[5];
  const float* b2  = (const float*)d_in[6];
  const float* cw1 = (const float*)d_in[7];
  const float* cb1 = (const float*)d_in[8];
  const float* cw2 = (const float*)d_in[9];
  const float* cb2 = (const float*)d_in[10];
  const float* cw3 = (const float*)d_in[11];
  const float* cb3 = (const float*)d_in[12];
  const float* fw1 = (const float*)d_in[13];
  const float* fb1 = (const float*)d_in[14];
  const float* fw2 = (const float*)d_in[15];
  const float* fb2 = (const float*)d_in[16];
  float* outp = (float*)d_out;

  int N = in_sizes[0] / 4;
  int E = in_sizes[1] / 2;
  size_t N8 = (size_t)N * 8;
  int nbN = (N + 255) / 256, nbE = (E + 255) / 256;

  float* wsf  = (float*)d_ws;
  float* A    = wsf;
  float* Bb   = A + N8;              // A2 for layer 2
  int* degI   = (int*)(Bb + N8);     // N ints
  int* cursor = degI + N;            // N ints
  float* dinv = (float*)(cursor + N);// N floats
  int* cum    = (int*)(dinv + N);    // BG+1 ints
  float* D0   = (float*)(((uintptr_t)(cum + BG + 1) + 255) & ~(uintptr_t)255);
  float* D1   = D0 + (size_t)BG * 8 * MAXN;

  // CSR temporaries aliased into D1 (D1 first written by conv1, after fill/gathers)
  int* rowptr = (int*)D1;            // N+1
  int* adj    = rowptr + (N + 1);    // E
  int* bsum   = adj + E;             // nbN

  // --- boundaries + zero degI/cursor (fused, no atomics) ---
  k_bounds<<<nbN, 256, 0, stream>>>(batch, cum, degI, cursor, N);

  // --- CSR build ---
  k_deg_int<<<nbE, 256, 0, stream>>>(ei + E, degI, E);
  k_blocksum<<<nbN, 256, 0, stream>>>(degI, bsum, N);
  k_scanb<<<1, 256, 0, stream>>>(bsum, nbN);
  k_rowptr<<<nbN, 256, 0, stream>>>(degI, bsum, rowptr, dinv, N);
  k_fill<<<nbE, 256, 0, stream>>>(ei, ei + E, rowptr, cursor, adj, E);

  // --- GCN (gather, no atomics) ---
  k_xw1<<<nbN, 256, 0, stream>>>(x, W1, dinv, A, N);
  k_gather_l1<<<nbN, 256, 0, stream>>>(A, rowptr, adj, dinv, b1, W2, Bb, N);
  k_zero_pad<<<BG, 256, 0, stream>>>(D0, cum);   // zero only pos >= cnt
  k_gather_l2<<<nbN, 256, 0, stream>>>(Bb, rowptr, adj, dinv, b2, batch, cum, D0, N);

  // --- convs: scalar weights; NCO=8 on conv2/conv3 to lengthen FMA blocks per load ---
  k_conv<8, 16, 2000, 1><<<dim3(BG, 1, 4), 256, 0, stream>>>(D0, cw1, cb1, D1);
  k_conv<16, 32, 1000, 1><<<dim3(BG, 1, 2), 256, 0, stream>>>(D1, cw2, cb2, D0);
  k_conv<32, 64, 500, 2><<<dim3(BG, 2, 1), 256, 0, stream>>>(D0, cw3, cb3, D1);

  // --- fused segment means + MLP ---
  k_head<<<BG, 256, 0, stream>>>(D1, cum, fw1, fb1, fw2, fb2, outp);
}

// Round 18
// 142.807 us; speedup vs baseline: 1.2827x; 1.1407x over previous
//
#include <hip/hip_runtime.h>
#include <cstdint>

constexpr int BG = 256;        // graphs
constexpr int MAXN = 2000;
constexpr int NPARTS = 10;

// dynamic-LDS layout (dwords)
constexpr int R0_DW = 16512;   // max(t1 16x1008, t3 64x258)
constexpr int R1_DW = 16256;   // max(in 8x2008, t2 32x508)
constexpr int SEG_DW = 640;
constexpr int HID_DW = 128;
constexpr int SM_BYTES = (R0_DW + R1_DW + SEG_DW + HID_DW) * 4;   // 134,144 B

// ---------------- batch boundaries + zero degI/cursor (fused; batch is sorted) ----------------

__global__ void k_bounds(const int* __restrict__ batch, int* __restrict__ cum,
                         int* __restrict__ degI, int* __restrict__ cursor, int N) {
  int i = blockIdx.x * blockDim.x + threadIdx.x;
  if (i >= N) return;
  degI[i] = 0;
  cursor[i] = 0;
  int b = batch[i];
  if (i == 0) cum[b] = 0;
  else if (batch[i - 1] != b) cum[b] = i;
  if (i == N - 1) cum[BG] = N;
}

// ---------------- CSR build ----------------

__global__ void k_deg_int(const int* __restrict__ dst, int* __restrict__ deg, int E) {
  int e = blockIdx.x * blockDim.x + threadIdx.x;
  if (e < E) atomicAdd(&deg[dst[e]], 1);
}

__global__ void k_blocksum(const int* __restrict__ deg, int* __restrict__ bsum, int N) {
  __shared__ int sd[256];
  int i = blockIdx.x * 256 + threadIdx.x;
  sd[threadIdx.x] = (i < N) ? deg[i] : 0;
  __syncthreads();
  for (int s = 128; s > 0; s >>= 1) {
    if (threadIdx.x < s) sd[threadIdx.x] += sd[threadIdx.x + s];
    __syncthreads();
  }
  if (threadIdx.x == 0) bsum[blockIdx.x] = sd[0];
}

__global__ __launch_bounds__(256)
void k_scanb(int* __restrict__ bsum, int nb) {
  __shared__ int part[256];
  int tid = threadIdx.x;
  int per = (nb + 255) / 256;
  int beg = tid * per;
  int end = beg + per; if (end > nb) end = nb;
  int s = 0;
  for (int i = beg; i < end; i++) s += bsum[i];
  part[tid] = s;
  __syncthreads();
  for (int off = 1; off < 256; off <<= 1) {
    int t = (tid >= off) ? part[tid - off] : 0;
    __syncthreads();
    part[tid] += t;
    __syncthreads();
  }
  int run = part[tid] - s;
  for (int i = beg; i < end; i++) { int v = bsum[i]; bsum[i] = run; run += v; }
}

__global__ void k_rowptr(const int* __restrict__ deg, const int* __restrict__ bsum,
                         int* __restrict__ rowptr, float* __restrict__ dinvf, int N) {
  __shared__ int sc[256];
  int tid = threadIdx.x;
  int i = blockIdx.x * 256 + tid;
  int v = (i < N) ? deg[i] : 0;
  sc[tid] = v;
  __syncthreads();
  for (int off = 1; off < 256; off <<= 1) {
    int t = (tid >= off) ? sc[tid - off] : 0;
    __syncthreads();
    sc[tid] += t;
    __syncthreads();
  }
  if (i < N) {
    rowptr[i] = bsum[blockIdx.x] + sc[tid] - v;
    dinvf[i] = rsqrtf((float)v + 1.0f);
  }
  if (i == N - 1) rowptr[N] = bsum[blockIdx.x] + sc[tid];
}

__global__ void k_fill(const int* __restrict__ src, const int* __restrict__ dst,
                       const int* __restrict__ rowptr, int* __restrict__ cursor,
                       int* __restrict__ adj, int E) {
  int e = blockIdx.x * blockDim.x + threadIdx.x;
  if (e >= E) return;
  int d = dst[e];
  int p = atomicAdd(&cursor[d], 1);
  adj[rowptr[d] + p] = src[e];
}

// ---------------- GCN dense parts ----------------

__global__ void k_xw1(const float* __restrict__ x, const float* __restrict__ W1,
                      const float* __restrict__ dinv, float* __restrict__ A, int N) {
  int i = blockIdx.x * blockDim.x + threadIdx.x;
  if (i >= N) return;
  float4 xi = ((const float4*)x)[i];
  float di = dinv[i];
  #pragma unroll
  for (int c = 0; c < 8; c++) {
    float s = xi.x * W1[c] + xi.y * W1[8 + c] + xi.z * W1[16 + c] + xi.w * W1[24 + c];
    A[(size_t)i * 8 + c] = s * di;
  }
}

__global__ void k_gather_l1(const float* __restrict__ A, const int* __restrict__ rowptr,
                            const int* __restrict__ adj, const float* __restrict__ dinv,
                            const float* __restrict__ b1, const float* __restrict__ W2,
                            float* __restrict__ A2, int N) {
  int i = blockIdx.x * blockDim.x + threadIdx.x;
  if (i >= N) return;
  const float4* Ai = (const float4*)(A + (size_t)i * 8);
  float4 s0 = Ai[0], s1 = Ai[1];
  int beg = rowptr[i], end = rowptr[i + 1];
  for (int j = beg; j < end; j++) {
    const float4* As = (const float4*)(A + (size_t)adj[j] * 8);
    float4 a0 = As[0], a1 = As[1];
    s0.x += a0.x; s0.y += a0.y; s0.z += a0.z; s0.w += a0.w;
    s1.x += a1.x; s1.y += a1.y; s1.z += a1.z; s1.w += a1.w;
  }
  float di = dinv[i];
  float h[8];
  h[0] = fmaxf(s0.x * di + b1[0], 0.f); h[1] = fmaxf(s0.y * di + b1[1], 0.f);
  h[2] = fmaxf(s0.z * di + b1[2], 0.f); h[3] = fmaxf(s0.w * di + b1[3], 0.f);
  h[4] = fmaxf(s1.x * di + b1[4], 0.f); h[5] = fmaxf(s1.y * di + b1[5], 0.f);
  h[6] = fmaxf(s1.z * di + b1[6], 0.f); h[7] = fmaxf(s1.w * di + b1[7], 0.f);
  #pragma unroll
  for (int c = 0; c < 8; c++) {
    float a = 0.f;
    #pragma unroll
    for (int k = 0; k < 8; k++) a += h[k] * W2[k * 8 + c];
    A2[(size_t)i * 8 + c] = a * di;
  }
}

// layer-2 gather, COMPACT output H2[i][8] (no dense scatter)
__global__ void k_gather_l2(const float* __restrict__ A2, const int* __restrict__ rowptr,
                            const int* __restrict__ adj, const float* __restrict__ dinv,
                            const float* __restrict__ b2, float* __restrict__ H2, int N) {
  int i = blockIdx.x * blockDim.x + threadIdx.x;
  if (i >= N) return;
  const float4* Ai = (const float4*)(A2 + (size_t)i * 8);
  float4 s0 = Ai[0], s1 = Ai[1];
  int beg = rowptr[i], end = rowptr[i + 1];
  for (int j = beg; j < end; j++) {
    const float4* As = (const float4*)(A2 + (size_t)adj[j] * 8);
    float4 a0 = As[0], a1 = As[1];
    s0.x += a0.x; s0.y += a0.y; s0.z += a0.z; s0.w += a0.w;
    s1.x += a1.x; s1.y += a1.y; s1.z += a1.z; s1.w += a1.w;
  }
  float di = dinv[i];
  float4 o0, o1;
  o0.x = fmaxf(s0.x * di + b2[0], 0.f); o0.y = fmaxf(s0.y * di + b2[1], 0.f);
  o0.z = fmaxf(s0.z * di + b2[2], 0.f); o0.w = fmaxf(s0.w * di + b2[3], 0.f);
  o1.x = fmaxf(s1.x * di + b2[4], 0.f); o1.y = fmaxf(s1.y * di + b2[5], 0.f);
  o1.z = fmaxf(s1.z * di + b2[6], 0.f); o1.w = fmaxf(s1.w * di + b2[7], 0.f);
  float4* op = (float4*)(H2 + (size_t)i * 8);
  op[0] = o0; op[1] = o1;
}

// ---------------- fused conv1->conv2->conv3 + segmean + MLP, all in LDS ----------------
// Padded row layout: row stride = L+8 dwords, data at [4, 4+L), zeros in pads.
// conv task split: wave -> 8 out-channels (oct) x 128-pooled chunk; lane -> 2 pooled.
// Reads: 3 contiguous ds_read_b128 per ci (lane stride 4 dwords -> conflict-free).
template<int CIN, int COUT, int L>
__device__ void conv_lds(const float* __restrict__ sin, float* __restrict__ sout,
                         const float* __restrict__ w, const float* __restrict__ bias,
                         int tid) {
  constexpr int LOUT = L / 2;
  constexpr int LSI = L + 8;
  constexpr int LSO = LOUT + 8;
  constexpr int NOCT = COUT / 8;
  constexpr int NCH = (LOUT + 127) / 128;
  const int wv = __builtin_amdgcn_readfirstlane(tid >> 6);
  const int lane = tid & 63;

  for (int task = wv; task < NOCT * NCH; task += 8) {
    int oct = task / NCH, ch = task - oct * NCH;
    int pb = ch * 128 + 2 * lane;            // 2 pooled per lane (even)
    int rb = pb <= LOUT - 2 ? pb : LOUT - 2; // clamp reads (stores masked)
    float acc[8][4];
    #pragma unroll
    for (int g = 0; g < 8; g++)
      #pragma unroll
      for (int t = 0; t < 4; t++) acc[g][t] = 0.f;

    for (int ci = 0; ci < CIN; ci++) {
      const float* rp = sin + ci * LSI + 2 * rb;   // dwords 2rb .. 2rb+11
      float4 qa = *(const float4*)(rp);
      float4 qb = *(const float4*)(rp + 4);
      float4 qc = *(const float4*)(rp + 8);
      float r[12] = {qa.x, qa.y, qa.z, qa.w, qb.x, qb.y, qb.z, qb.w,
                     qc.x, qc.y, qc.z, qc.w};
      #pragma unroll
      for (int g = 0; g < 8; g++) {
        const float* wg = w + ((size_t)(oct * 8 + g) * CIN + ci) * 5;  // wave-uniform
        float v0 = wg[0], v1 = wg[1], v2 = wg[2], v3 = wg[3], v4 = wg[4];
        #pragma unroll
        for (int t = 0; t < 4; t++)   // conv col 2rb+t needs padded idx 2rb+2+t..2rb+6+t
          acc[g][t] += v0 * r[t + 2] + v1 * r[t + 3] + v2 * r[t + 4]
                     + v3 * r[t + 5] + v4 * r[t + 6];
      }
    }
    if (pb < LOUT) {
      #pragma unroll
      for (int g = 0; g < 8; g++) {
        int co = oct * 8 + g;
        float bv = bias[co];
        float y0 = fmaxf(acc[g][0] + bv, 0.f);
        float y1 = fmaxf(acc[g][1] + bv, 0.f);
        float y2 = fmaxf(acc[g][2] + bv, 0.f);
        float y3 = fmaxf(acc[g][3] + bv, 0.f);
        *(float2*)(sout + co * LSO + 4 + pb) =
            make_float2(0.5f * (y0 + y1), 0.5f * (y2 + y3));
      }
    }
  }
  // zero output pads: [0,4) and [4+LOUT, LSO) per row
  for (int idx = tid; idx < COUT * 8; idx += 512) {
    int row = idx >> 3, k = idx & 7;
    int d = (k < 4) ? k : (LOUT + k);
    sout[row * LSO + d] = 0.f;
  }
}

__global__ __launch_bounds__(512)
void k_fused(const float* __restrict__ H2, const int* __restrict__ cum,
             const float* __restrict__ cw1, const float* __restrict__ cb1,
             const float* __restrict__ cw2, const float* __restrict__ cb2,
             const float* __restrict__ cw3, const float* __restrict__ cb3,
             const float* __restrict__ fw1, const float* __restrict__ fb1,
             const float* __restrict__ fw2, const float* __restrict__ fb2,
             float* __restrict__ out) {
  extern __shared__ float sm[];
  float* R0 = sm;                 // t1 (16x1008) / t3 (64x258)
  float* R1 = sm + R0_DW;         // in (8x2008) / t2 (32x508)
  float* seg = R1 + R1_DW;        // 640
  float* hid = seg + SEG_DW;      // 100 used
  const int b = blockIdx.x;
  const int tid = threadIdx.x;
  const int base = cum[b];
  const int cnt = cum[b + 1] - base;

  // zero input buffer (pads + beyond-cnt), then scatter H2 transposed
  for (int d = tid * 4; d < 8 * 2008; d += 512 * 4)
    *(float4*)(R1 + d) = make_float4(0.f, 0.f, 0.f, 0.f);
  __syncthreads();
  for (int n = tid; n < cnt; n += 512) {
    const float4* hp = (const float4*)(H2 + (size_t)(base + n) * 8);
    float4 h0 = hp[0], h1 = hp[1];
    R1[0 * 2008 + 4 + n] = h0.x; R1[1 * 2008 + 4 + n] = h0.y;
    R1[2 * 2008 + 4 + n] = h0.z; R1[3 * 2008 + 4 + n] = h0.w;
    R1[4 * 2008 + 4 + n] = h1.x; R1[5 * 2008 + 4 + n] = h1.y;
    R1[6 * 2008 + 4 + n] = h1.z; R1[7 * 2008 + 4 + n] = h1.w;
  }
  __syncthreads();

  conv_lds<8, 16, 2000>(R1, R0, cw1, cb1, tid);
  __syncthreads();
  conv_lds<16, 32, 1000>(R0, R1, cw2, cb2, tid);
  __syncthreads();
  conv_lds<32, 64, 500>(R1, R0, cw3, cb3, tid);
  __syncthreads();

  // segment means over t3 (R0, stride 258, data at +4)
  int valid = cnt >> 3;
  int sb = valid / NPARTS, rem = valid % NPARTS;
  for (int idx = tid; idx < 640; idx += 512) {
    int c = idx / NPARTS, j = idx - c * NPARTS;
    int size = sb + (j < rem ? 1 : 0);
    int start = j * sb + (j < rem ? j : rem);
    const float* p = R0 + c * 258 + 4 + start;
    float s = 0.f;
    for (int t = 0; t < size; t++) s += p[t];
    seg[idx] = s / (float)size;
  }
  __syncthreads();
  if (tid < 100) {
    float acc = fb1[tid];
    for (int k = 0; k < 640; k++) acc += seg[k] * fw1[(size_t)k * 100 + tid];
    hid[tid] = fmaxf(acc, 0.f);
  }
  __syncthreads();
  if (tid < 2) {
    float acc = fb2[tid];
    for (int k = 0; k < 100; k++) acc += hid[k] * fw2[k * 2 + tid];
    out[b * 2 + tid] = acc;
  }
}

extern "C" void kernel_launch(void* const* d_in, const int* in_sizes, int n_in,
                              void* d_out, int out_size, void* d_ws, size_t ws_size,
                              hipStream_t stream) {
  const float* x   = (const float*)d_in[0];
  const int*   ei  = (const int*)d_in[1];
  const int* batch = (const int*)d_in[2];
  const float* W1  = (const float*)d_in[3];
  const float* b1  = (const float*)d_in[4];
  const float* W2  = (const float*)d_in[5];
  const float* b2  = (const float*)d_in[6];
  const float* cw1 = (const float*)d_in[7];
  const float* cb1 = (const float*)d_in[8];
  const float* cw2 = (const float*)d_in[9];
  const float* cb2 = (const float*)d_in[10];
  const float* cw3 = (const float*)d_in[11];
  const float* cb3 = (const float*)d_in[12];
  const float* fw1 = (const float*)d_in[13];
  const float* fb1 = (const float*)d_in[14];
  const float* fw2 = (const float*)d_in[15];
  const float* fb2 = (const float*)d_in[16];
  float* outp = (float*)d_out;

  int N = in_sizes[0] / 4;
  int E = in_sizes[1] / 2;
  size_t N8 = (size_t)N * 8;
  int nbN = (N + 255) / 256, nbE = (E + 255) / 256;

  float* wsf  = (float*)d_ws;
  float* A    = wsf;                  // N8
  float* Bb   = A + N8;               // N8 (A2)
  float* H2   = Bb + N8;              // N8
  int* degI   = (int*)(H2 + N8);      // N
  int* cursor = degI + N;             // N
  float* dinv = (float*)(cursor + N); // N
  int* cum    = (int*)(dinv + N);     // BG+1
  int* rowptr = cum + BG + 1;         // N+1
  int* adj    = rowptr + N + 1;       // E
  int* bsum   = adj + E;              // nbN

  static int attr_set = 0;
  hipFuncSetAttribute((const void*)k_fused,
                      hipFuncAttributeMaxDynamicSharedMemorySize, SM_BYTES);
  (void)attr_set;

  // --- boundaries + zero degI/cursor (fused, no atomics) ---
  k_bounds<<<nbN, 256, 0, stream>>>(batch, cum, degI, cursor, N);

  // --- CSR build ---
  k_deg_int<<<nbE, 256, 0, stream>>>(ei + E, degI, E);
  k_blocksum<<<nbN, 256, 0, stream>>>(degI, bsum, N);
  k_scanb<<<1, 256, 0, stream>>>(bsum, nbN);
  k_rowptr<<<nbN, 256, 0, stream>>>(degI, bsum, rowptr, dinv, N);
  k_fill<<<nbE, 256, 0, stream>>>(ei, ei + E, rowptr, cursor, adj, E);

  // --- GCN (gather, no atomics) ---
  k_xw1<<<nbN, 256, 0, stream>>>(x, W1, dinv, A, N);
  k_gather_l1<<<nbN, 256, 0, stream>>>(A, rowptr, adj, dinv, b1, W2, Bb, N);
  k_gather_l2<<<nbN, 256, 0, stream>>>(Bb, rowptr, adj, dinv, b2, H2, N);

  // --- fused conv pyramid + segmean + MLP, one block per graph, all in LDS ---
  k_fused<<<BG, 512, SM_BYTES, stream>>>(H2, cum, cw1, cb1, cw2, cb2, cw3, cb3,
                                         fw1, fb1, fw2, fb2, outp);
}

// Round 19
// 136.352 us; speedup vs baseline: 1.3434x; 1.0473x over previous
//
#include <hip/hip_runtime.h>
#include <cstdint>

constexpr int BG = 256;        // graphs
constexpr int MAXN = 2000;
constexpr int NPARTS = 10;

// truncated pipeline lengths (counts <= 1455 -> valid <= 181):
// in 1488 cols (stride 1496, pad 4+4), t1 744 (stride 752), t2 372 (stride 380),
// t3 184 (stride 184, no pad). All unread tail positions provably never consumed.
constexpr int R0_DW = 12032;   // max(t1 16x752, t3 64x184=11776)
constexpr int R1_DW = 12160;   // max(in 8x1496=11968, t2 32x380)
constexpr int SEG_DW = 640;
constexpr int PART_DW = 512;
constexpr int SM_BYTES = (R0_DW + R1_DW + SEG_DW + PART_DW) * 4;   // 101,376 B

// ---------------- batch boundaries + zero degI/cursor (fused; batch is sorted) ----------------

__global__ void k_bounds(const int* __restrict__ batch, int* __restrict__ cum,
                         int* __restrict__ degI, int* __restrict__ cursor, int N) {
  int i = blockIdx.x * blockDim.x + threadIdx.x;
  if (i >= N) return;
  degI[i] = 0;
  cursor[i] = 0;
  int b = batch[i];
  if (i == 0) cum[b] = 0;
  else if (batch[i - 1] != b) cum[b] = i;
  if (i == N - 1) cum[BG] = N;
}

// ---------------- CSR build ----------------

__global__ void k_deg_int(const int* __restrict__ dst, int* __restrict__ deg, int E) {
  int e = blockIdx.x * blockDim.x + threadIdx.x;
  if (e < E) atomicAdd(&deg[dst[e]], 1);
}

__global__ void k_blocksum(const int* __restrict__ deg, int* __restrict__ bsum, int N) {
  __shared__ int sd[256];
  int i = blockIdx.x * 256 + threadIdx.x;
  sd[threadIdx.x] = (i < N) ? deg[i] : 0;
  __syncthreads();
  for (int s = 128; s > 0; s >>= 1) {
    if (threadIdx.x < s) sd[threadIdx.x] += sd[threadIdx.x + s];
    __syncthreads();
  }
  if (threadIdx.x == 0) bsum[blockIdx.x] = sd[0];
}

__global__ __launch_bounds__(256)
void k_scanb(int* __restrict__ bsum, int nb) {
  __shared__ int part[256];
  int tid = threadIdx.x;
  int per = (nb + 255) / 256;
  int beg = tid * per;
  int end = beg + per; if (end > nb) end = nb;
  int s = 0;
  for (int i = beg; i < end; i++) s += bsum[i];
  part[tid] = s;
  __syncthreads();
  for (int off = 1; off < 256; off <<= 1) {
    int t = (tid >= off) ? part[tid - off] : 0;
    __syncthreads();
    part[tid] += t;
    __syncthreads();
  }
  int run = part[tid] - s;
  for (int i = beg; i < end; i++) { int v = bsum[i]; bsum[i] = run; run += v; }
}

__global__ void k_rowptr(const int* __restrict__ deg, const int* __restrict__ bsum,
                         int* __restrict__ rowptr, float* __restrict__ dinvf, int N) {
  __shared__ int sc[256];
  int tid = threadIdx.x;
  int i = blockIdx.x * 256 + tid;
  int v = (i < N) ? deg[i] : 0;
  sc[tid] = v;
  __syncthreads();
  for (int off = 1; off < 256; off <<= 1) {
    int t = (tid >= off) ? sc[tid - off] : 0;
    __syncthreads();
    sc[tid] += t;
    __syncthreads();
  }
  if (i < N) {
    rowptr[i] = bsum[blockIdx.x] + sc[tid] - v;
    dinvf[i] = rsqrtf((float)v + 1.0f);
  }
  if (i == N - 1) rowptr[N] = bsum[blockIdx.x] + sc[tid];
}

__global__ void k_fill(const int* __restrict__ src, const int* __restrict__ dst,
                       const int* __restrict__ rowptr, int* __restrict__ cursor,
                       int* __restrict__ adj, int E) {
  int e = blockIdx.x * blockDim.x + threadIdx.x;
  if (e >= E) return;
  int d = dst[e];
  int p = atomicAdd(&cursor[d], 1);
  adj[rowptr[d] + p] = src[e];
}

// ---------------- GCN dense parts ----------------

__global__ void k_xw1(const float* __restrict__ x, const float* __restrict__ W1,
                      const float* __restrict__ dinv, float* __restrict__ A, int N) {
  int i = blockIdx.x * blockDim.x + threadIdx.x;
  if (i >= N) return;
  float4 xi = ((const float4*)x)[i];
  float di = dinv[i];
  #pragma unroll
  for (int c = 0; c < 8; c++) {
    float s = xi.x * W1[c] + xi.y * W1[8 + c] + xi.z * W1[16 + c] + xi.w * W1[24 + c];
    A[(size_t)i * 8 + c] = s * di;
  }
}

__global__ void k_gather_l1(const float* __restrict__ A, const int* __restrict__ rowptr,
                            const int* __restrict__ adj, const float* __restrict__ dinv,
                            const float* __restrict__ b1, const float* __restrict__ W2,
                            float* __restrict__ A2, int N) {
  int i = blockIdx.x * blockDim.x + threadIdx.x;
  if (i >= N) return;
  const float4* Ai = (const float4*)(A + (size_t)i * 8);
  float4 s0 = Ai[0], s1 = Ai[1];
  int beg = rowptr[i], end = rowptr[i + 1];
  for (int j = beg; j < end; j++) {
    const float4* As = (const float4*)(A + (size_t)adj[j] * 8);
    float4 a0 = As[0], a1 = As[1];
    s0.x += a0.x; s0.y += a0.y; s0.z += a0.z; s0.w += a0.w;
    s1.x += a1.x; s1.y += a1.y; s1.z += a1.z; s1.w += a1.w;
  }
  float di = dinv[i];
  float h[8];
  h[0] = fmaxf(s0.x * di + b1[0], 0.f); h[1] = fmaxf(s0.y * di + b1[1], 0.f);
  h[2] = fmaxf(s0.z * di + b1[2], 0.f); h[3] = fmaxf(s0.w * di + b1[3], 0.f);
  h[4] = fmaxf(s1.x * di + b1[4], 0.f); h[5] = fmaxf(s1.y * di + b1[5], 0.f);
  h[6] = fmaxf(s1.z * di + b1[6], 0.f); h[7] = fmaxf(s1.w * di + b1[7], 0.f);
  #pragma unroll
  for (int c = 0; c < 8; c++) {
    float a = 0.f;
    #pragma unroll
    for (int k = 0; k < 8; k++) a += h[k] * W2[k * 8 + c];
    A2[(size_t)i * 8 + c] = a * di;
  }
}

// layer-2 gather, COMPACT output H2[i][8]
__global__ void k_gather_l2(const float* __restrict__ A2, const int* __restrict__ rowptr,
                            const int* __restrict__ adj, const float* __restrict__ dinv,
                            const float* __restrict__ b2, float* __restrict__ H2, int N) {
  int i = blockIdx.x * blockDim.x + threadIdx.x;
  if (i >= N) return;
  const float4* Ai = (const float4*)(A2 + (size_t)i * 8);
  float4 s0 = Ai[0], s1 = Ai[1];
  int beg = rowptr[i], end = rowptr[i + 1];
  for (int j = beg; j < end; j++) {
    const float4* As = (const float4*)(A2 + (size_t)adj[j] * 8);
    float4 a0 = As[0], a1 = As[1];
    s0.x += a0.x; s0.y += a0.y; s0.z += a0.z; s0.w += a0.w;
    s1.x += a1.x; s1.y += a1.y; s1.z += a1.z; s1.w += a1.w;
  }
  float di = dinv[i];
  float4 o0, o1;
  o0.x = fmaxf(s0.x * di + b2[0], 0.f); o0.y = fmaxf(s0.y * di + b2[1], 0.f);
  o0.z = fmaxf(s0.z * di + b2[2], 0.f); o0.w = fmaxf(s0.w * di + b2[3], 0.f);
  o1.x = fmaxf(s1.x * di + b2[4], 0.f); o1.y = fmaxf(s1.y * di + b2[5], 0.f);
  o1.z = fmaxf(s1.z * di + b2[6], 0.f); o1.w = fmaxf(s1.w * di + b2[7], 0.f);
  float4* op = (float4*)(H2 + (size_t)i * 8);
  op[0] = o0; op[1] = o1;
}

// ---------------- fused conv pyramid + segmean + MLP ----------------
// conv task: wave -> 8 out-channels (oct) x CHUNK pooled; lane -> NP pooled positions.
// oct-minor task order spreads partial chunks across waves.
template<int CIN, int COUT, int LSI, int LOUT, int LSO, int OPAD, int NP>
__device__ __forceinline__ void conv_lds(const float* __restrict__ sin,
                                         float* __restrict__ sout,
                                         const float* __restrict__ w,
                                         const float* __restrict__ bias, int tid) {
  constexpr int NOCT = COUT / 8;
  constexpr int CHUNK = 64 * NP;
  constexpr int NCH = (LOUT + CHUNK - 1) / CHUNK;
  constexpr int NB = (2 * NP + 6 + 3) / 4;   // b128 reads per ci
  const int wv = __builtin_amdgcn_readfirstlane(tid >> 6);
  const int lane = tid & 63;

  for (int task = wv; task < NOCT * NCH; task += 8) {
    const int oct = __builtin_amdgcn_readfirstlane(task % NOCT);
    const int ch = task / NOCT;
    const int pb = ch * CHUNK + NP * lane;
    const int rb = pb <= (LOUT - NP) ? pb : (LOUT - NP);

    float acc[8][2 * NP];
    #pragma unroll
    for (int g = 0; g < 8; g++)
      #pragma unroll
      for (int t = 0; t < 2 * NP; t++) acc[g][t] = 0.f;

    for (int ci = 0; ci < CIN; ci++) {
      const float* rp = sin + ci * LSI + 2 * rb;   // 16B aligned (rb even)
      float r[4 * NB];
      #pragma unroll
      for (int b = 0; b < NB; b++) {
        float4 q = *(const float4*)(rp + 4 * b);
        r[4 * b] = q.x; r[4 * b + 1] = q.y; r[4 * b + 2] = q.z; r[4 * b + 3] = q.w;
      }
      #pragma unroll
      for (int g = 0; g < 8; g++) {
        const float* wg = w + ((size_t)(oct * 8 + g) * CIN + ci) * 5;  // s_load
        float v0 = wg[0], v1 = wg[1], v2 = wg[2], v3 = wg[3], v4 = wg[4];
        #pragma unroll
        for (int t = 0; t < 2 * NP; t++)
          acc[g][t] += v0 * r[t + 2] + v1 * r[t + 3] + v2 * r[t + 4]
                     + v3 * r[t + 5] + v4 * r[t + 6];
      }
    }

    #pragma unroll
    for (int g = 0; g < 8; g++) {
      int co = oct * 8 + g;
      float bv = bias[co];
      float pl[NP];
      #pragma unroll
      for (int m = 0; m < NP; m++) {
        float y0 = fmaxf(acc[g][2 * m] + bv, 0.f);
        float y1 = fmaxf(acc[g][2 * m + 1] + bv, 0.f);
        pl[m] = 0.5f * (y0 + y1);
      }
      float* op = sout + co * LSO + OPAD + pb;
      if constexpr (NP == 4) {
        if (pb + 4 <= LOUT) {
          *(float4*)op = make_float4(pl[0], pl[1], pl[2], pl[3]);
        } else {
          #pragma unroll
          for (int m = 0; m < 4; m++) if (pb + m < LOUT) op[m] = pl[m];
        }
      } else {
        if (pb + 2 <= LOUT) {
          *(float2*)op = make_float2(pl[0], pl[1]);
        } else {
          if (pb < LOUT) op[0] = pl[0];
        }
      }
    }
  }
  // zero output pads
  if constexpr (OPAD > 0) {
    constexpr int TAIL = LSO - OPAD - LOUT;
    constexpr int PPR = OPAD + TAIL;          // pads per row
    for (int idx = tid; idx < COUT * PPR; idx += 512) {
      int row = idx / PPR, k = idx % PPR;
      int d = (k < OPAD) ? k : (LOUT + k);
      sout[row * LSO + d] = 0.f;
    }
  }
}

__global__ __launch_bounds__(512, 2)
void k_fused(const float* __restrict__ H2, const int* __restrict__ cum,
             const float* __restrict__ cw1, const float* __restrict__ cb1,
             const float* __restrict__ cw2, const float* __restrict__ cb2,
             const float* __restrict__ cw3, const float* __restrict__ cb3,
             const float* __restrict__ fw1, const float* __restrict__ fb1,
             const float* __restrict__ fw2, const float* __restrict__ fb2,
             float* __restrict__ out) {
  extern __shared__ float sm[];
  float* R0 = sm;                  // t1 (16x752) / t3 (64x184)
  float* R1 = sm + R0_DW;          // in (8x1496) / t2 (32x380)
  float* seg = R1 + R1_DW;         // 640
  float* part = seg + SEG_DW;      // 512
  const int b = blockIdx.x;
  const int tid = threadIdx.x;
  const int base = cum[b];
  const int cnt0 = cum[b + 1] - base;
  const int cnt = cnt0 < 1488 ? cnt0 : 1488;   // safety clamp (dataset max 1455)

  // zero input pads: front 4/row + tail [4+cnt, 1496)
  if (tid < 32) R1[(tid >> 2) * 1496 + (tid & 3)] = 0.f;
  #pragma unroll
  for (int r = 0; r < 8; r++)
    for (int d = 4 + cnt + tid; d < 1496; d += 512) R1[r * 1496 + d] = 0.f;
  __syncthreads();
  // scatter H2 transposed (only first 1488 nodes feed the head)
  for (int n = tid; n < cnt; n += 512) {
    const float4* hp = (const float4*)(H2 + (size_t)(base + n) * 8);
    float4 h0 = hp[0], h1 = hp[1];
    R1[0 * 1496 + 4 + n] = h0.x; R1[1 * 1496 + 4 + n] = h0.y;
    R1[2 * 1496 + 4 + n] = h0.z; R1[3 * 1496 + 4 + n] = h0.w;
    R1[4 * 1496 + 4 + n] = h1.x; R1[5 * 1496 + 4 + n] = h1.y;
    R1[6 * 1496 + 4 + n] = h1.z; R1[7 * 1496 + 4 + n] = h1.w;
  }
  __syncthreads();

  conv_lds<8, 16, 1496, 744, 752, 4, 4>(R1, R0, cw1, cb1, tid);
  __syncthreads();
  conv_lds<16, 32, 752, 372, 380, 4, 4>(R0, R1, cw2, cb2, tid);
  __syncthreads();
  conv_lds<32, 64, 380, 184, 184, 0, 2>(R1, R0, cw3, cb3, tid);
  __syncthreads();

  // segment means over t3 (stride 184, no pad)
  int valid = cnt0 >> 3;
  int sb = valid / NPARTS, rem = valid % NPARTS;
  for (int idx = tid; idx < 640; idx += 512) {
    int c = idx / NPARTS, j = idx - c * NPARTS;
    int size = sb + (j < rem ? 1 : 0);
    int start = j * sb + (j < rem ? j : rem);
    const float* p = R0 + c * 184 + start;
    float s = 0.f;
    for (int t = 0; t < size; t++) s += p[t];
    seg[idx] = s / (float)size;
  }
  __syncthreads();

  // MLP: 4 threads per neuron, 160-k partials
  {
    int n = tid >> 2, q = tid & 3;
    float acc = 0.f;
    if (n < 100) {
      int k0 = q * 160;
      for (int k = k0; k < k0 + 160; k++) acc += seg[k] * fw1[(size_t)k * 100 + n];
      part[(q << 7) + n] = acc;
    }
  }
  __syncthreads();
  if (tid < 100) {
    float h = part[tid] + part[128 + tid] + part[256 + tid] + part[384 + tid] + fb1[tid];
    part[tid] = fmaxf(h, 0.f);
  }
  __syncthreads();
  if (tid < 2) {
    float acc = fb2[tid];
    for (int k = 0; k < 100; k++) acc += part[k] * fw2[k * 2 + tid];
    out[b * 2 + tid] = acc;
  }
}

extern "C" void kernel_launch(void* const* d_in, const int* in_sizes, int n_in,
                              void* d_out, int out_size, void* d_ws, size_t ws_size,
                              hipStream_t stream) {
  const float* x   = (const float*)d_in[0];
  const int*   ei  = (const int*)d_in[1];
  const int* batch = (const int*)d_in[2];
  const float* W1  = (const float*)d_in[3];
  const float* b1  = (const float*)d_in[4];
  const float* W2  = (const float*)d_in[5];
  const float* b2  = (const float*)d_in[6];
  const float* cw1 = (const float*)d_in[7];
  const float* cb1 = (const float*)d_in[8];
  const float* cw2 = (const float*)d_in[9];
  const float* cb2 = (const float*)d_in[10];
  const float* cw3 = (const float*)d_in[11];
  const float* cb3 = (const float*)d_in[12];
  const float* fw1 = (const float*)d_in[13];
  const float* fb1 = (const float*)d_in[14];
  const float* fw2 = (const float*)d_in[15];
  const float* fb2 = (const float*)d_in[16];
  float* outp = (float*)d_out;

  int N = in_sizes[0] / 4;
  int E = in_sizes[1] / 2;
  size_t N8 = (size_t)N * 8;
  int nbN = (N + 255) / 256, nbE = (E + 255) / 256;

  float* wsf  = (float*)d_ws;
  float* A    = wsf;                  // N8
  float* Bb   = A + N8;               // N8 (A2)
  float* H2   = Bb + N8;              // N8
  int* degI   = (int*)(H2 + N8);      // N
  int* cursor = degI + N;             // N
  float* dinv = (float*)(cursor + N); // N
  int* cum    = (int*)(dinv + N);     // BG+1
  int* rowptr = cum + BG + 1;         // N+1
  int* adj    = rowptr + N + 1;       // E
  int* bsum   = adj + E;              // nbN

  hipFuncSetAttribute((const void*)k_fused,
                      hipFuncAttributeMaxDynamicSharedMemorySize, SM_BYTES);

  // --- boundaries + zero degI/cursor (fused, no atomics) ---
  k_bounds<<<nbN, 256, 0, stream>>>(batch, cum, degI, cursor, N);

  // --- CSR build ---
  k_deg_int<<<nbE, 256, 0, stream>>>(ei + E, degI, E);
  k_blocksum<<<nbN, 256, 0, stream>>>(degI, bsum, N);
  k_scanb<<<1, 256, 0, stream>>>(bsum, nbN);
  k_rowptr<<<nbN, 256, 0, stream>>>(degI, bsum, rowptr, dinv, N);
  k_fill<<<nbE, 256, 0, stream>>>(ei, ei + E, rowptr, cursor, adj, E);

  // --- GCN (gather, no atomics) ---
  k_xw1<<<nbN, 256, 0, stream>>>(x, W1, dinv, A, N);
  k_gather_l1<<<nbN, 256, 0, stream>>>(A, rowptr, adj, dinv, b1, W2, Bb, N);
  k_gather_l2<<<nbN, 256, 0, stream>>>(Bb, rowptr, adj, dinv, b2, H2, N);

  // --- fused truncated conv pyramid + segmean + MLP ---
  k_fused<<<BG, 512, SM_BYTES, stream>>>(H2, cum, cw1, cb1, cw2, cb2, cw3, cb3,
                                         fw1, fb1, fw2, fb2, outp);
}